// Round 1
// baseline (16.847 us; speedup 1.0000x reference)
//
#include <hip/hip_runtime.h>

#define BB 8
#define HH 256
#define WW 512
#define NLANES 5
#define KORD 4            // ORDER+1
#define RIDGE_D 1e-6
#define EPS_DEN_F 1e-5f

// ---------------------------------------------------------------------------
// Kernel 1: per-row label histogram with x-moments.
// grid = BB*HH blocks, block = 64 (one wave per image row).
// stats layout: [b][lane][row][3] ints: {count, sum_x, sum_x2}
// ---------------------------------------------------------------------------
__global__ void row_hist_kernel(const int* __restrict__ labels,
                                int* __restrict__ stats) {
    const int row  = blockIdx.x;      // b*HH + i
    const int lane = threadIdx.x;     // 0..63
    const int* rp = labels + (size_t)row * WW;

    int c[NLANES], sx[NLANES], sxx[NLANES];
#pragma unroll
    for (int l = 0; l < NLANES; ++l) { c[l] = 0; sx[l] = 0; sxx[l] = 0; }

#pragma unroll
    for (int h = 0; h < 2; ++h) {
        const int j0 = h * 256 + lane * 4;
        const int4 v = *reinterpret_cast<const int4*>(rp + j0);
        const int vv[4] = {v.x, v.y, v.z, v.w};
#pragma unroll
        for (int q = 0; q < 4; ++q) {
            const int j   = j0 + q;
            const int lab = vv[q];
#pragma unroll
            for (int l = 0; l < NLANES; ++l) {
                const int mm = (lab == l + 1) ? 1 : 0;
                c[l]   += mm;
                sx[l]  += mm * j;
                sxx[l] += mm * j * j;
            }
        }
    }

#pragma unroll
    for (int l = 0; l < NLANES; ++l) {
#pragma unroll
        for (int off = 32; off > 0; off >>= 1) {
            c[l]   += __shfl_down(c[l],   off);
            sx[l]  += __shfl_down(sx[l],  off);
            sxx[l] += __shfl_down(sxx[l], off);
        }
    }

    if (lane == 0) {
        const int b = row >> 8;
        const int i = row & 255;
#pragma unroll
        for (int l = 0; l < NLANES; ++l) {
            int* o = stats + (((b * NLANES + l) * HH + i) * 3);
            o[0] = c[l]; o[1] = sx[l]; o[2] = sxx[l];
        }
    }
}

// ---------------------------------------------------------------------------
// Kernel 2: per (batch, lane) polynomial fit + loss terms.
// grid = BB*NLANES blocks, block = 64.  Each lane handles 4 rows.
// Pass 1: accumulate A (10 sym entries), rhs(4), mad, cnt in double.
// Lane 0: pivoted 4x4 solve.  Pass 2: direct residual sum (no cancellation).
// ---------------------------------------------------------------------------
__global__ void lane_fit_kernel(const float* __restrict__ hp,
                                const int* __restrict__ stats,
                                double* __restrict__ out_ll,
                                double* __restrict__ out_valid) {
    const int blk  = blockIdx.x;       // 0..39
    const int b    = blk / NLANES;
    const int l    = blk % NLANES;
    const int lane = threadIdx.x;      // 0..63

    const float p0 = hp[b * 6 + 0];
    const float p1 = hp[b * 6 + 1];
    const float p2 = hp[b * 6 + 2];
    const float p3 = hp[b * 6 + 3];
    const float p5 = hp[b * 6 + 5];
    const float p4 = hp[b * 6 + 4];

    const int* sb = stats + ((b * NLANES + l) * HH) * 3;

    double A[10];
    double r[4];
    double mad = 0.0, cnt = 0.0;
#pragma unroll
    for (int u = 0; u < 10; ++u) A[u] = 0.0;
#pragma unroll
    for (int u = 0; u < 4; ++u)  r[u] = 0.0;

    // ---- pass 1 ----
#pragma unroll
    for (int k = 0; k < 4; ++k) {
        const int i = lane + 64 * k;
        const float yf = (float)i;
        float den = p5 * yf + 1.0f;            // f32, matching reference pole math
        if (fabsf(den) < EPS_DEN_F) den = EPS_DEN_F;
        const float ypf = (p3 * yf + p4) / den;
        const float qf  = p1 * yf + p2;

        const double dend = (double)den;
        const double yp   = (double)ypf;
        const double Yv[4] = { yp * yp * yp, yp * yp, yp, 1.0 };

        const int* s = sb + i * 3;
        const double cd  = (double)s[0];
        const double sxd = (double)s[1];
        const double a0  = (double)p0 / dend;
        const double bq  = (double)qf / dend;
        const double rw  = a0 * sxd + bq * cd;   // sum of xp over masked cols

        int idx = 0;
#pragma unroll
        for (int u = 0; u < 4; ++u)
#pragma unroll
            for (int v2 = u; v2 < 4; ++v2)
                A[idx++] += cd * Yv[u] * Yv[v2];
#pragma unroll
        for (int u = 0; u < 4; ++u) r[u] += Yv[u] * rw;

        mad += cd * fabs(dend);
        cnt += cd;
    }

    // wave reduction of 16 doubles
#pragma unroll
    for (int u = 0; u < 10; ++u)
#pragma unroll
        for (int off = 32; off > 0; off >>= 1) A[u] += __shfl_down(A[u], off);
#pragma unroll
    for (int u = 0; u < 4; ++u)
#pragma unroll
        for (int off = 32; off > 0; off >>= 1) r[u] += __shfl_down(r[u], off);
#pragma unroll
    for (int off = 32; off > 0; off >>= 1) { mad += __shfl_down(mad, off);
                                             cnt += __shfl_down(cnt, off); }

    // ---- solve (lane 0) ----
    double wl[4] = {0.0, 0.0, 0.0, 0.0};
    if (lane == 0) {
        double M[4][5];
        int idx = 0;
        for (int u = 0; u < 4; ++u)
            for (int v2 = u; v2 < 4; ++v2) {
                M[u][v2] = A[idx];
                M[v2][u] = A[idx];
                ++idx;
            }
        for (int u = 0; u < 4; ++u) M[u][u] += RIDGE_D;
        for (int u = 0; u < 4; ++u) M[u][4] = r[u];

        // Gaussian elimination with partial pivoting
        for (int col = 0; col < 4; ++col) {
            int piv = col;
            double pmax = fabs(M[col][col]);
            for (int rr = col + 1; rr < 4; ++rr) {
                const double av = fabs(M[rr][col]);
                if (av > pmax) { pmax = av; piv = rr; }
            }
            if (piv != col)
                for (int cc = col; cc < 5; ++cc) {
                    const double t = M[col][cc]; M[col][cc] = M[piv][cc]; M[piv][cc] = t;
                }
            const double pv = M[col][col];
            const double inv = (pv != 0.0) ? 1.0 / pv : 0.0;
            for (int rr = col + 1; rr < 4; ++rr) {
                const double f = M[rr][col] * inv;
                for (int cc = col; cc < 5; ++cc) M[rr][cc] -= f * M[col][cc];
            }
        }
        for (int u = 3; u >= 0; --u) {
            double acc = M[u][4];
            for (int cc = u + 1; cc < 4; ++cc) acc -= M[u][cc] * wl[cc];
            const double pv = M[u][u];
            wl[u] = (pv != 0.0) ? acc / pv : 0.0;
        }
    }
    double w0 = __shfl(wl[0], 0);
    double w1 = __shfl(wl[1], 0);
    double w2 = __shfl(wl[2], 0);
    double w3 = __shfl(wl[3], 0);

    // ---- pass 2: direct residual accumulation ----
    double msesum = 0.0;
#pragma unroll
    for (int k = 0; k < 4; ++k) {
        const int i = lane + 64 * k;
        const float yf = (float)i;
        float den = p5 * yf + 1.0f;
        if (fabsf(den) < EPS_DEN_F) den = EPS_DEN_F;
        const float ypf = (p3 * yf + p4) / den;
        const float qf  = p1 * yf + p2;

        const double dend = (double)den;
        const double yp   = (double)ypf;
        const int* s = sb + i * 3;
        const double cd   = (double)s[0];
        const double sxd  = (double)s[1];
        const double sxxd = (double)s[2];
        const double a0   = (double)p0 / dend;
        const double bq   = (double)qf / dend;

        const double t = ((w0 * yp + w1) * yp + w2) * yp + w3;   // x_pred(row)
        const double e = bq - t;
        msesum += a0 * a0 * sxxd + 2.0 * a0 * e * sxd + e * e * cd;
    }
#pragma unroll
    for (int off = 32; off > 0; off >>= 1) msesum += __shfl_down(msesum, off);

    if (lane == 0) {
        const double cnt_safe = fmax(cnt, 1.0);
        const double mse = msesum / cnt_safe;
        const double mdm = mad / cnt_safe;
        out_ll[blk]    = mse * mdm;
        out_valid[blk] = (cnt >= (double)KORD) ? 1.0 : 0.0;
    }
}

// ---------------------------------------------------------------------------
// Kernel 3: reduce 40 (lane_loss, valid) pairs -> scalar loss
// ---------------------------------------------------------------------------
__global__ void finalize_kernel(const double* __restrict__ ll,
                                const double* __restrict__ valid,
                                float* __restrict__ out) {
    const int lane = threadIdx.x;
    double num = 0.0, nv = 0.0;
    if (lane < BB * NLANES) {
        const double v = valid[lane];
        num = v * ll[lane];
        nv  = v;
    }
#pragma unroll
    for (int off = 32; off > 0; off >>= 1) {
        num += __shfl_down(num, off);
        nv  += __shfl_down(nv,  off);
    }
    if (lane == 0) {
        const double loss = (nv > 0.0) ? num / fmax(nv, 1.0) : 0.0;
        out[0] = (float)loss;
    }
}

// ---------------------------------------------------------------------------
extern "C" void kernel_launch(void* const* d_in, const int* in_sizes, int n_in,
                              void* d_out, int out_size, void* d_ws, size_t ws_size,
                              hipStream_t stream) {
    const float* hp     = (const float*)d_in[0];
    const int*   labels = (const int*)d_in[1];
    float*       out    = (float*)d_out;

    // workspace layout
    int*    stats = (int*)d_ws;                         // 8*5*256*3 ints = 122880 B
    double* ll    = (double*)((char*)d_ws + BB * NLANES * HH * 3 * sizeof(int));
    double* valid = ll + BB * NLANES;

    row_hist_kernel<<<BB * HH, 64, 0, stream>>>(labels, stats);
    lane_fit_kernel<<<BB * NLANES, 64, 0, stream>>>(hp, stats, ll, valid);
    finalize_kernel<<<1, 64, 0, stream>>>(ll, valid, out);
}

// Round 2
// 15.400 us; speedup vs baseline: 1.0940x; 1.0940x over previous
//
#include <hip/hip_runtime.h>

#define BB 8
#define HH 256
#define WW 512
#define NLANES 5
#define KORD 4            // ORDER+1
#define RIDGE_D 1e-6
#define EPS_DEN_F 1e-5f

#define STATS_INTS (BB * NLANES * HH * 3)      // 30720 ints = 122880 B

// ---------------------------------------------------------------------------
// Kernel 1: per-row label histogram with x-moments.
// grid = BB*HH blocks, block = 64 (one wave per image row).
// stats layout: [b][lane][row][3] ints: {count, sum_x, sum_x2}
// Block 0 additionally zero-inits the finalize accumulators.
// ---------------------------------------------------------------------------
__global__ void row_hist_kernel(const int* __restrict__ labels,
                                int* __restrict__ stats,
                                double* __restrict__ acc,        // [num, nv]
                                unsigned int* __restrict__ counter) {
    if (blockIdx.x == 0 && threadIdx.x == 0) {
        acc[0] = 0.0;
        acc[1] = 0.0;
        *counter = 0u;
    }

    const int row  = blockIdx.x;      // b*HH + i
    const int lane = threadIdx.x;     // 0..63
    const int* rp = labels + (size_t)row * WW;

    int c[NLANES], sx[NLANES], sxx[NLANES];
#pragma unroll
    for (int l = 0; l < NLANES; ++l) { c[l] = 0; sx[l] = 0; sxx[l] = 0; }

#pragma unroll
    for (int h = 0; h < 2; ++h) {
        const int j0 = h * 256 + lane * 4;
        const int4 v = *reinterpret_cast<const int4*>(rp + j0);
        const int vv[4] = {v.x, v.y, v.z, v.w};
#pragma unroll
        for (int q = 0; q < 4; ++q) {
            const int j   = j0 + q;
            const int lab = vv[q];
#pragma unroll
            for (int l = 0; l < NLANES; ++l) {
                const int mm = (lab == l + 1) ? 1 : 0;
                c[l]   += mm;
                sx[l]  += mm * j;
                sxx[l] += mm * j * j;
            }
        }
    }

#pragma unroll
    for (int l = 0; l < NLANES; ++l) {
#pragma unroll
        for (int off = 32; off > 0; off >>= 1) {
            c[l]   += __shfl_down(c[l],   off);
            sx[l]  += __shfl_down(sx[l],  off);
            sxx[l] += __shfl_down(sxx[l], off);
        }
    }

    if (lane == 0) {
        const int b = row >> 8;
        const int i = row & 255;
#pragma unroll
        for (int l = 0; l < NLANES; ++l) {
            int* o = stats + (((b * NLANES + l) * HH + i) * 3);
            o[0] = c[l]; o[1] = sx[l]; o[2] = sxx[l];
        }
    }
}

// ---------------------------------------------------------------------------
// Kernel 2: per (batch, lane) polynomial fit + loss + grid finalize.
// grid = BB*NLANES blocks, block = 64.  Each lane handles 4 rows.
// Pass 1: accumulate A (10 sym entries), rhs(4), mad, cnt in double,
//         butterfly-reduced so ALL lanes hold the totals.
// Solve:  pivot-free unrolled 4x4 elimination (A is SPD + ridge), all in
//         named registers, done redundantly by every lane (no divergence,
//         no scratch, no broadcast).
// Pass 2: direct residual sum (no cancellation).
// Tail:   device-scope atomics + last-block counter -> write d_out.
// ---------------------------------------------------------------------------
__global__ void lane_fit_kernel(const float* __restrict__ hp,
                                const int* __restrict__ stats,
                                double* __restrict__ acc,        // [num, nv]
                                unsigned int* __restrict__ counter,
                                float* __restrict__ out) {
    const int blk  = blockIdx.x;       // 0..39
    const int b    = blk / NLANES;
    const int l    = blk % NLANES;
    const int lane = threadIdx.x;      // 0..63

    const float p0 = hp[b * 6 + 0];
    const float p1 = hp[b * 6 + 1];
    const float p2 = hp[b * 6 + 2];
    const float p3 = hp[b * 6 + 3];
    const float p4 = hp[b * 6 + 4];
    const float p5 = hp[b * 6 + 5];

    const int* sb = stats + ((b * NLANES + l) * HH) * 3;

    double A[10];
    double r[4];
    double mad = 0.0, cnt = 0.0;
#pragma unroll
    for (int u = 0; u < 10; ++u) A[u] = 0.0;
#pragma unroll
    for (int u = 0; u < 4; ++u)  r[u] = 0.0;

    // ---- pass 1 ----
#pragma unroll
    for (int k = 0; k < 4; ++k) {
        const int i = lane + 64 * k;
        const float yf = (float)i;
        float den = p5 * yf + 1.0f;            // f32, matching reference pole math
        if (fabsf(den) < EPS_DEN_F) den = EPS_DEN_F;
        const float ypf = (p3 * yf + p4) / den;
        const float qf  = p1 * yf + p2;

        const double dend = (double)den;
        const double yp   = (double)ypf;
        const double Yv[4] = { yp * yp * yp, yp * yp, yp, 1.0 };

        const int* s = sb + i * 3;
        const double cd  = (double)s[0];
        const double sxd = (double)s[1];
        const double a0  = (double)p0 / dend;
        const double bq  = (double)qf / dend;
        const double rw  = a0 * sxd + bq * cd;   // sum of xp over masked cols

        int idx = 0;
#pragma unroll
        for (int u = 0; u < 4; ++u)
#pragma unroll
            for (int v2 = u; v2 < 4; ++v2)
                A[idx++] += cd * Yv[u] * Yv[v2];
#pragma unroll
        for (int u = 0; u < 4; ++u) r[u] += Yv[u] * rw;

        mad += cd * fabs(dend);
        cnt += cd;
    }

    // butterfly reduction: all lanes end with the full sums
#pragma unroll
    for (int u = 0; u < 10; ++u)
#pragma unroll
        for (int off = 32; off > 0; off >>= 1) A[u] += __shfl_xor(A[u], off);
#pragma unroll
    for (int u = 0; u < 4; ++u)
#pragma unroll
        for (int off = 32; off > 0; off >>= 1) r[u] += __shfl_xor(r[u], off);
#pragma unroll
    for (int off = 32; off > 0; off >>= 1) { mad += __shfl_xor(mad, off);
                                             cnt += __shfl_xor(cnt, off); }

    // ---- pivot-free unrolled 4x4 solve (SPD + ridge), all registers ----
    double m00 = A[0] + RIDGE_D, m01 = A[1],           m02 = A[2],           m03 = A[3];
    double m11 = A[4] + RIDGE_D, m12 = A[5],           m13 = A[6];
    double m22 = A[7] + RIDGE_D, m23 = A[8];
    double m33 = A[9] + RIDGE_D;
    double r0 = r[0], r1 = r[1], r2 = r[2], r3 = r[3];

    const double inv0 = 1.0 / m00;
    {
        const double f10 = m01 * inv0, f20 = m02 * inv0, f30 = m03 * inv0;
        m11 -= f10 * m01; m12 -= f10 * m02; m13 -= f10 * m03;
        m22 -= f20 * m02; m23 -= f20 * m03;
        m33 -= f30 * m03;
        r1  -= f10 * r0;  r2  -= f20 * r0;  r3  -= f30 * r0;
    }
    const double inv1 = 1.0 / m11;
    {
        const double f21 = m12 * inv1, f31 = m13 * inv1;
        m22 -= f21 * m12; m23 -= f21 * m13;
        m33 -= f31 * m13;
        r2  -= f21 * r1;  r3  -= f31 * r1;
    }
    const double inv2 = 1.0 / m22;
    {
        const double f32v = m23 * inv2;
        m33 -= f32v * m23;
        r3  -= f32v * r2;
    }
    const double w3 = (m33 != 0.0) ? r3 / m33 : 0.0;
    const double w2 = (r2 - m23 * w3) * inv2;
    const double w1 = (r1 - m12 * w2 - m13 * w3) * inv1;
    const double w0 = (r0 - m01 * w1 - m02 * w2 - m03 * w3) * inv0;

    // ---- pass 2: direct residual accumulation ----
    double msesum = 0.0;
#pragma unroll
    for (int k = 0; k < 4; ++k) {
        const int i = lane + 64 * k;
        const float yf = (float)i;
        float den = p5 * yf + 1.0f;
        if (fabsf(den) < EPS_DEN_F) den = EPS_DEN_F;
        const float ypf = (p3 * yf + p4) / den;
        const float qf  = p1 * yf + p2;

        const double dend = (double)den;
        const double yp   = (double)ypf;
        const int* s = sb + i * 3;
        const double cd   = (double)s[0];
        const double sxd  = (double)s[1];
        const double sxxd = (double)s[2];
        const double a0   = (double)p0 / dend;
        const double bq   = (double)qf / dend;

        const double t = ((w0 * yp + w1) * yp + w2) * yp + w3;   // x_pred(row)
        const double e = bq - t;
        msesum += a0 * a0 * sxxd + 2.0 * a0 * e * sxd + e * e * cd;
    }
#pragma unroll
    for (int off = 32; off > 0; off >>= 1) msesum += __shfl_down(msesum, off);

    // ---- finalize: atomics + last-block writes d_out ----
    if (lane == 0) {
        const double cnt_safe = fmax(cnt, 1.0);
        const double mse = msesum / cnt_safe;
        const double mdm = mad / cnt_safe;
        const double ll  = mse * mdm;
        const double vv  = (cnt >= (double)KORD) ? 1.0 : 0.0;

        atomicAdd(&acc[0], vv * ll);
        atomicAdd(&acc[1], vv);
        __threadfence();
        const unsigned int prev = atomicAdd(counter, 1u);
        if (prev == (unsigned int)(BB * NLANES - 1)) {
            const double num = atomicAdd(&acc[0], 0.0);   // coherent read
            const double nv  = atomicAdd(&acc[1], 0.0);
            const double loss = (nv > 0.0) ? num / fmax(nv, 1.0) : 0.0;
            out[0] = (float)loss;
        }
    }
}

// ---------------------------------------------------------------------------
extern "C" void kernel_launch(void* const* d_in, const int* in_sizes, int n_in,
                              void* d_out, int out_size, void* d_ws, size_t ws_size,
                              hipStream_t stream) {
    const float* hp     = (const float*)d_in[0];
    const int*   labels = (const int*)d_in[1];
    float*       out    = (float*)d_out;

    // workspace layout
    int*          stats   = (int*)d_ws;                        // 122880 B
    double*       acc     = (double*)((char*)d_ws + STATS_INTS * sizeof(int)); // 16 B
    unsigned int* counter = (unsigned int*)(acc + 2);

    row_hist_kernel<<<BB * HH, 64, 0, stream>>>(labels, stats, acc, counter);
    lane_fit_kernel<<<BB * NLANES, 64, 0, stream>>>(hp, stats, acc, counter, out);
}